// Round 5
// baseline (469.619 us; speedup 1.0000x reference)
//
#include <hip/hip_runtime.h>
#include <math.h>

#define BB 128
#define TT 2048
#define DD 256
#define AA 128
#define ROWS (BB*TT)     // 262144
#define NTILES 16        // 16-row tiles per block -> 256 rows/block
#define NBLK (ROWS/16/NTILES)   // 1024 blocks, 8 per batch
#define BPB 8            // blocks per batch

typedef __attribute__((ext_vector_type(8))) short bf16x8;
typedef __attribute__((ext_vector_type(4))) float f32x4;

__device__ __forceinline__ unsigned short f2bf(float f) {
    unsigned int u = __builtin_bit_cast(unsigned int, f);
    unsigned int r = (u + 0x7FFFu + ((u >> 16) & 1u)) >> 16;   // RNE
    return (unsigned short)r;
}
__device__ __forceinline__ float bf2f(unsigned short s) {
    unsigned int u = ((unsigned int)s) << 16;
    return __builtin_bit_cast(float, u);
}

// ws layout (floats):
// [0, NBLK*256)            pnum[NBLK][256]  partial numerators
// [NBLK*256, +NBLK)        pz[NBLK]         partial Z
// ~1.03 MB

// ---------------- Fused: logits + exp + weighted accumulate -------------
// 512 thr = 8 waves; wave wv owns a-cols [wv*16,+16) with W hi/lo in regs.
// Per 16x256 x-tile: reg-stage fp32 -> split-bf16 into swizzled LDS frags
// (double buffered) -> 3x8 MFMA -> tanh*ctx -> row logit -> e=exp ->
// nacc[j] += e[row]*x (x still in regs). Partials out per block.
__global__ __launch_bounds__(512, 4) void k_fused(
    const float* __restrict__ x, const float* __restrict__ w,
    const float* __restrict__ bias, const float* __restrict__ ctx,
    float* __restrict__ pnum, float* __restrict__ pz)
{
    __shared__ bf16x8 ldsx[2][1024];   // 32 KB: hi frags 0..511, lo 512..1023
    __shared__ float pred[8][16];
    __shared__ float erow[16];
    __shared__ float redbuf[16][256];  // 16 KB: final nacc reduction

    const int tid  = threadIdx.x;
    const int lane = tid & 63;
    const int wv   = tid >> 6;

    // ---- W fragments (hi/lo) into registers ----
    const int colg  = wv * 16 + (lane & 15);
    const int krow0 = (lane >> 4) * 8;
    bf16x8 wh[8], wl[8];
    #pragma unroll
    for (int ks = 0; ks < 8; ++ks) {
        union { bf16x8 v; unsigned short u[8]; } H, L;
        #pragma unroll
        for (int j = 0; j < 8; ++j) {
            float f = w[(ks * 32 + krow0 + j) * AA + colg];
            unsigned short h = f2bf(f);
            H.u[j] = h;
            L.u[j] = f2bf(f - bf2f(h));
        }
        wh[ks] = H.v; wl[ks] = L.v;
    }
    const float bias_l = bias[colg];
    const float ctx_l  = ctx[colg];

    // ---- staging geometry ----
    const int srow  = tid >> 5;                 // 0..15 tile row
    const int kg    = tid & 31;                 // 0..31 (8-col group)
    const int sks   = kg >> 2;                  // K-step 0..7
    const int slot  = ((kg & 3) << 4) + srow;   // logical frag slot
    const int wfrag = sks * 64 + (slot ^ sks);  // XOR bank swizzle

    const int tile0 = blockIdx.x * NTILES;

    float ldA[8], ldB[8], nacc[8];
    #pragma unroll
    for (int j = 0; j < 8; ++j) nacc[j] = 0.f;
    float zacc = 0.f;

    auto load_regs = [&](int tile, float (&ld)[8]) {
        const float* src = x + (size_t)tile * (16 * DD) + srow * DD + kg * 8;
        float4 a = *(const float4*)(src);
        float4 b = *(const float4*)(src + 4);
        ld[0]=a.x; ld[1]=a.y; ld[2]=a.z; ld[3]=a.w;
        ld[4]=b.x; ld[5]=b.y; ld[6]=b.z; ld[7]=b.w;
    };
    auto write_lds = [&](int buf, const float (&ld)[8]) {
        union { bf16x8 v; unsigned short u[8]; } H, L;
        #pragma unroll
        for (int j = 0; j < 8; ++j) {
            unsigned short h = f2bf(ld[j]);
            H.u[j] = h;
            L.u[j] = f2bf(ld[j] - bf2f(h));
        }
        ldsx[buf][wfrag]       = H.v;
        ldsx[buf][512 + wfrag] = L.v;
    };

    // step(i, CUR, NXT): prefetch tile i+1 into NXT, MFMA tile i, epilogue,
    // stage NXT to LDS, weighted-accumulate with CUR.
    auto step = [&](int i, float (&cur)[8], float (&nxt)[8]) {
        const int tile = tile0 + i;
        if (i + 1 < NTILES) load_regs(tile + 1, nxt);

        const int buf = i & 1;
        f32x4 acc = {0.f, 0.f, 0.f, 0.f};
        #pragma unroll
        for (int ks = 0; ks < 8; ++ks) {
            const int rf = ks * 64 + (lane ^ ks);
            bf16x8 ah = ldsx[buf][rf];
            bf16x8 al = ldsx[buf][512 + rf];
            acc = __builtin_amdgcn_mfma_f32_16x16x32_bf16(ah, wh[ks], acc, 0, 0, 0);
            acc = __builtin_amdgcn_mfma_f32_16x16x32_bf16(al, wh[ks], acc, 0, 0, 0);
            acc = __builtin_amdgcn_mfma_f32_16x16x32_bf16(ah, wl[ks], acc, 0, 0, 0);
        }

        // tanh*ctx + 16-col reduce (within wave)
        #pragma unroll
        for (int r = 0; r < 4; ++r) {
            float v = tanhf(acc[r] + bias_l) * ctx_l;
            v += __shfl_xor(v, 1, 64);
            v += __shfl_xor(v, 2, 64);
            v += __shfl_xor(v, 4, 64);
            v += __shfl_xor(v, 8, 64);
            if ((lane & 15) == 0) pred[wv][(lane >> 4) * 4 + r] = v;
        }
        __syncthreads();                  // pred ready; buf^1 readers done

        if (tid < 16) {                   // one thread per row: logit -> e
            float s = pred[0][tid] + pred[1][tid] + pred[2][tid] + pred[3][tid]
                    + pred[4][tid] + pred[5][tid] + pred[6][tid] + pred[7][tid];
            float e = expf(s);
            erow[tid] = e;
            zacc += e;
        }
        if (i + 1 < NTILES) write_lds(buf ^ 1, nxt);
        __syncthreads();                  // erow ready; next buf staged

        const float ew = erow[srow];
        #pragma unroll
        for (int j = 0; j < 8; ++j)
            nacc[j] = fmaf(ew, cur[j], nacc[j]);
    };

    load_regs(tile0, ldA);
    write_lds(0, ldA);
    __syncthreads();

    for (int i = 0; i < NTILES; i += 2) {
        step(i,     ldA, ldB);
        step(i + 1, ldB, ldA);
    }

    // ---- block-level reduction of nacc (16 row-owners per column) ----
    #pragma unroll
    for (int j = 0; j < 8; ++j)
        redbuf[srow][kg * 8 + j] = nacc[j];
    __syncthreads();
    if (tid < 256) {
        float s = 0.f;
        #pragma unroll
        for (int r = 0; r < 16; ++r) s += redbuf[r][tid];
        pnum[(size_t)blockIdx.x * 256 + tid] = s;
    }
    if (tid < 16) {
        float z = zacc;
        z += __shfl_xor(z, 1, 64);
        z += __shfl_xor(z, 2, 64);
        z += __shfl_xor(z, 4, 64);
        z += __shfl_xor(z, 8, 64);
        if (tid == 0) pz[blockIdx.x] = z;
    }
}

// ---------------- Final: combine 8 chunks per batch, normalize ----------
__global__ __launch_bounds__(256) void k_out(
    const float* __restrict__ pnum, const float* __restrict__ pz,
    float* __restrict__ out)
{
    const int b = blockIdx.x;
    const int d = threadIdx.x;
    float s = 0.f, z = 0.f;
    #pragma unroll
    for (int c = 0; c < BPB; ++c) {
        s += pnum[((size_t)(b * BPB + c)) * 256 + d];
        z += pz[b * BPB + c];
    }
    out[b * DD + d] = s / (z + 1e-10f);
}

extern "C" void kernel_launch(void* const* d_in, const int* in_sizes, int n_in,
                              void* d_out, int out_size, void* d_ws, size_t ws_size,
                              hipStream_t stream)
{
    const float* x    = (const float*)d_in[0];   // [128,2048,256]
    const float* w    = (const float*)d_in[1];   // [256,128]
    const float* bias = (const float*)d_in[2];   // [128]
    const float* ctx  = (const float*)d_in[3];   // [128,1]
    float* out = (float*)d_out;                  // [128,256]

    float* ws   = (float*)d_ws;
    float* pnum = ws;                            // NBLK*256
    float* pz   = ws + (size_t)NBLK * 256;       // NBLK

    k_fused<<<NBLK, 512, 0, stream>>>(x, w, bias, ctx, pnum, pz);
    k_out  <<<BB,   256, 0, stream>>>(pnum, pz, out);
}